// Round 4
// baseline (80.323 us; speedup 1.0000x reference)
//
#include <hip/hip_runtime.h>

// LGNLayer: retina matvec -> threshold fire -> LGN matvec+relu -> WTA row update.
// All f32. Outputs concatenated: new_firing[8192], lgn_act[2048],
// lgn_weights_new[2048*8192], lgn_threshold_new[2048].
//
// 3 kernels:
//   k_retina: 256MB stream matvec; also inits the ws argmax slot (runs-before k_lgn).
//   k_lgn:    64MB read + 64MB copy-out fused; computes act, packed-atomicMax argmax,
//             writes thr_out[row] (non-winner value).
//   k_wta:    winner-only: row update + thr_out[idx] patch (single block).

constexpr int N_RET = 8192;
constexpr int N_LGN = 2048;
constexpr float ETA = 0.1f;
constexpr float MU_WTS = 2.5f;

// native clang vector type: __builtin_nontemporal_* requires scalar/vector types
typedef float vf4 __attribute__((ext_vector_type(4)));

__device__ __forceinline__ vf4 ntload4(const float* p) {
    return __builtin_nontemporal_load(reinterpret_cast<const vf4*>(p));
}
__device__ __forceinline__ void ntstore4(float* p, vf4 v) {
    __builtin_nontemporal_store(v, reinterpret_cast<vf4*>(p));
}
__device__ __forceinline__ vf4 ld4(const float* p) {
    return *reinterpret_cast<const vf4*>(p);
}
__device__ __forceinline__ void st4(float* p, vf4 v) {
    *reinterpret_cast<vf4*>(p) = v;
}

// ---------- K1: new_firing = (retina_weights @ is_firing > retina_threshold) ----------
__global__ __launch_bounds__(256) void k_retina(
    const float* __restrict__ rw, const float* __restrict__ rthr,
    const float* __restrict__ firing, float* __restrict__ new_firing,
    unsigned long long* __restrict__ ws_argmax)
{
    const int row = blockIdx.x;
    const int t = threadIdx.x;
    if (row == 0 && t == 0) *ws_argmax = 0ULL;   // loses to every pack(val>=0, idx<=2047)
    const float* __restrict__ wr = rw + (size_t)row * N_RET;
    vf4 acc = (vf4)(0.0f);
#pragma unroll
    for (int k = 0; k < (N_RET / 4) / 256; ++k) {   // 8 iterations
        const int j = (t + k * 256) * 4;
        const vf4 w = ntload4(wr + j);              // streaming, no reuse
        const vf4 f = ld4(firing + j);              // cached, reused by all blocks
        acc += w * f;
    }
    float v = (acc.x + acc.y) + (acc.z + acc.w);
#pragma unroll
    for (int off = 32; off > 0; off >>= 1) v += __shfl_down(v, off, 64);
    __shared__ float s[4];
    const int lane = t & 63, wv = t >> 6;
    if (lane == 0) s[wv] = v;
    __syncthreads();
    if (t == 0) {
        const float x = (s[0] + s[1]) + (s[2] + s[3]);
        new_firing[row] = (x > rthr[row]) ? 1.0f : 0.0f;
    }
}

// ---------- K2: lgn_act = relu(lgn_weights @ new_firing); fused copy + argmax + thr ----------
__global__ __launch_bounds__(256) void k_lgn(
    const float* __restrict__ lw, const float* __restrict__ firing,
    const float* __restrict__ lthr,
    float* __restrict__ lgn_act, float* __restrict__ w_out,
    float* __restrict__ thr_out, unsigned long long* __restrict__ ws_argmax)
{
    const int row = blockIdx.x;
    const int t = threadIdx.x;
    const float* __restrict__ wr = lw + (size_t)row * N_RET;
    float* __restrict__ wo = w_out + (size_t)row * N_RET;
    vf4 acc = (vf4)(0.0f);
#pragma unroll
    for (int k = 0; k < (N_RET / 4) / 256; ++k) {   // 8 iterations
        const int j = (t + k * 256) * 4;
        const vf4 w = ntload4(wr + j);              // streaming
        const vf4 f = ld4(firing + j);
        ntstore4(wo + j, w);                        // fused copy, streaming store
        acc += w * f;
    }
    float v = (acc.x + acc.y) + (acc.z + acc.w);
#pragma unroll
    for (int off = 32; off > 0; off >>= 1) v += __shfl_down(v, off, 64);
    __shared__ float s[4];
    const int lane = t & 63, wv = t >> 6;
    if (lane == 0) s[wv] = v;
    __syncthreads();
    if (t == 0) {
        const float x = fmaxf((s[0] + s[1]) + (s[2] + s[3]), 0.0f);
        lgn_act[row] = x;
        thr_out[row] = lthr[row];                   // non-winner value; k_wta patches winner
        const float a = fmaxf(x - lthr[row], 0.0f); // act for argmax
        // pack: val bits high (monotone for val>=0), ~row low (ties -> lowest row wins)
        const unsigned long long p =
            ((unsigned long long)__float_as_uint(a) << 32) | (unsigned)(~row);
        atomicMax(ws_argmax, p);                    // max is order-independent
    }
}

// ---------- K3: winner-only: row = ((w+a)+a)/mean*MU_WTS; thr_out[idx] patch ----------
__global__ __launch_bounds__(1024) void k_wta(
    const float* __restrict__ lthr,
    const float* __restrict__ lw, const float* __restrict__ firing,
    float* __restrict__ thr_out, float* __restrict__ w_out,
    const unsigned long long* __restrict__ ws_argmax)
{
    const unsigned long long p = *ws_argmax;
    const float val = __uint_as_float((unsigned)(p >> 32));
    if (!(val > 0.0f)) return;   // uniform: no update anywhere
    const int idx = (int)(~(unsigned)(p & 0xFFFFFFFFu));

    const int t = threadIdx.x;
    const int lane = t & 63, wv = t >> 6;
    if (t == 0) thr_out[idx] = lthr[idx] + 0.005f * val;

    const float* __restrict__ wr = lw + (size_t)idx * N_RET;
    float* __restrict__ wo = w_out + (size_t)idx * N_RET;
    const float av = 0.5f * (ETA * val);   // a = av * f for f in {0,1}

    vf4 x[2];
    float part = 0.0f;
#pragma unroll
    for (int k = 0; k < (N_RET / 4) / 1024; ++k) {   // 2 iterations
        const int j = (t + k * 1024) * 4;
        const vf4 w = ld4(wr + j);
        const vf4 f = ld4(firing + j);
        vf4 v = (w + av * f) + av * f;               // two half-additions, like ref
        x[k] = v;
        part += (v.x + v.y) + (v.z + v.w);
    }
#pragma unroll
    for (int off = 32; off > 0; off >>= 1) part += __shfl_down(part, off, 64);
    __shared__ float red[16];
    __shared__ float s_mean;
    if (lane == 0) red[wv] = part;
    __syncthreads();
    if (t == 0) {
        float sum = 0.0f;
#pragma unroll
        for (int k = 0; k < 16; ++k) sum += red[k];
        s_mean = sum / (float)N_RET;
    }
    __syncthreads();
    const float m = s_mean;
#pragma unroll
    for (int k = 0; k < (N_RET / 4) / 1024; ++k) {
        const int j = (t + k * 1024) * 4;
        st4(wo + j, x[k] / m * MU_WTS);
    }
}

extern "C" void kernel_launch(void* const* d_in, const int* in_sizes, int n_in,
                              void* d_out, int out_size, void* d_ws, size_t ws_size,
                              hipStream_t stream)
{
    const float* rw   = (const float*)d_in[0];   // retina_weights [8192, 8192]
    const float* rthr = (const float*)d_in[1];   // retina_threshold [8192]
    const float* lw   = (const float*)d_in[2];   // lgn_weights [2048, 8192]
    const float* lthr = (const float*)d_in[3];   // lgn_threshold [2048]
    const float* fir  = (const float*)d_in[4];   // is_firing [8192]

    float* out   = (float*)d_out;
    float* o_fir = out;                                         // [8192]
    float* o_act = out + N_RET;                                 // [2048]
    float* o_w   = out + N_RET + N_LGN;                         // [2048*8192]
    float* o_thr = out + N_RET + N_LGN + (size_t)N_LGN * N_RET; // [2048]
    unsigned long long* ws = (unsigned long long*)d_ws;

    hipLaunchKernelGGL(k_retina, dim3(N_RET), dim3(256),  0, stream, rw, rthr, fir, o_fir, ws);
    hipLaunchKernelGGL(k_lgn,    dim3(N_LGN), dim3(256),  0, stream, lw, o_fir, lthr, o_act, o_w, o_thr, ws);
    hipLaunchKernelGGL(k_wta,    dim3(1),     dim3(1024), 0, stream, lthr, lw, o_fir, o_thr, o_w, ws);
}